// Round 8
// baseline (27.261 us; speedup 1.0000x reference)
//
#include <hip/hip_runtime.h>

// AF4 group quantizer: 4096x4096 fp32, groups of 128 along columns.
// Persistent grid-stride waves: 2048 blocks x 256 thr = 8192 waves
// (32 waves/CU = max occupancy); each wave handles ~8 segments of 256
// contiguous elements with one-deep software prefetch (next segment's
// load in flight under current segment's reduce+quantize).
//
// Per segment: lanes 0..31 hold group A, lanes 32..63 group B. Reduction:
// ds_swizzle xor16 (crosses the 16-lane boundary) + 4 DPP VALU steps.
//
// Selection (fast path, smn<=0<=smx): magnitude-domain V-shape scan.
// d_k = fl(a - fl(sp*L_k)) is strictly V-shaped in fp32 (ladder gaps >=
// sp/12 >> ULP), so "take c_k when |d_k| < |d_{k-1}|" ends holding the
// argmin value with first-index tie behavior. Decisions bitwise-identical
// to the reference 16-candidate argmin (sign-split proof: for x>0 only the
// positive ladder or code 0 can win; dist to any negative code = |x|+|c|
// >= |x| = dist-to-0; ties keep the earlier index).

typedef float vfloat4 __attribute__((ext_vector_type(4)));

template <int CTRL>
__device__ __forceinline__ float dpp_mov_f32(float v) {
    return __int_as_float(__builtin_amdgcn_update_dpp(
        0, __float_as_int(v), CTRL, 0xF, 0xF, true));
}

__device__ __forceinline__ float swz_xor16_f32(float v) {
    return __int_as_float(__builtin_amdgcn_ds_swizzle(__float_as_int(v), 0x401F));
}

__device__ __forceinline__ vfloat4 quantize_seg(vfloat4 v, float percentile) {
    const float LEV1 = (float)(1.0 / 12.0);
    const float LEV2 = (float)(1.0 / 6.0);
    const float LEV3 = (float)(1.0 / 4.0);
    const float LEV4 = (float)(1.0 / 3.0);
    const float LEV5 = (float)(1.0 / 2.0);
    const float LEV6 = (float)(2.0 / 3.0);
    const float LEV7 = 1.0f;

    float vv[4] = {v.x, v.y, v.z, v.w};

    float mx = fmaxf(fmaxf(vv[0], vv[1]), fmaxf(vv[2], vv[3]));
    float mn = fminf(fminf(vv[0], vv[1]), fminf(vv[2], vv[3]));
    mx = fmaxf(mx, swz_xor16_f32(mx));
    mn = fminf(mn, swz_xor16_f32(mn));
    mx = fmaxf(mx, dpp_mov_f32<0xB1>(mx));   // quad_perm xor1
    mn = fminf(mn, dpp_mov_f32<0xB1>(mn));
    mx = fmaxf(mx, dpp_mov_f32<0x4E>(mx));   // quad_perm xor2
    mn = fminf(mn, dpp_mov_f32<0x4E>(mn));
    mx = fmaxf(mx, dpp_mov_f32<0x141>(mx));  // row_half_mirror
    mn = fminf(mn, dpp_mov_f32<0x141>(mn));
    mx = fmaxf(mx, dpp_mov_f32<0x140>(mx));  // row_mirror
    mn = fminf(mn, dpp_mov_f32<0x140>(mn));

    const float smx  = mx * percentile;
    const float smn  = mn * percentile;
    const float nabs = -smn;  // exact sign flip

    float r[4];

    if (smn <= 0.0f && smx >= 0.0f) {
        #pragma unroll
        for (int e = 0; e < 4; ++e) {
            const float xv = vv[e];
            const float a  = fabsf(xv);
            const float sp = (xv > 0.0f) ? smx : nabs;
            float dprev = a;     // d_0 = a - sp*0
            float bv    = 0.0f;  // best code magnitude so far
            #pragma unroll
            for (int k = 1; k < 8; ++k) {
                const float L = (k == 1) ? LEV1 : (k == 2) ? LEV2 : (k == 3) ? LEV3
                              : (k == 4) ? LEV4 : (k == 5) ? LEV5 : (k == 6) ? LEV6
                              : LEV7;
                const float c = sp * L;          // == reference codebook value
                const float d = a - c;           // same fp32 diff as reference
                if (fabsf(d) < fabsf(dprev)) bv = c;  // V-shape: last win = argmin
                dprev = d;
            }
            const unsigned sb = __float_as_uint(xv) & 0x80000000u;
            r[e] = __uint_as_float(__float_as_uint(bv) | sb);
        }
    } else {
        // exact 16-candidate fallback (degenerate one-sided groups)
        float code[16];
        code[0]  = smn * 0.0f; code[1]  = smn * LEV1; code[2]  = smn * LEV2;
        code[3]  = smn * LEV3; code[4]  = smn * LEV4; code[5]  = smn * LEV5;
        code[6]  = smn * LEV6; code[7]  = smn * LEV7;
        code[8]  = smx * 0.0f; code[9]  = smx * LEV1; code[10] = smx * LEV2;
        code[11] = smx * LEV3; code[12] = smx * LEV4; code[13] = smx * LEV5;
        code[14] = smx * LEV6; code[15] = smx * LEV7;
        #pragma unroll
        for (int e = 0; e < 4; ++e) {
            const float xv = vv[e];
            float bd = fabsf(xv - code[0]);
            float bv = code[0];
            #pragma unroll
            for (int k = 1; k < 16; ++k) {
                const float d = fabsf(xv - code[k]);
                if (d < bd) { bd = d; bv = code[k]; }
            }
            r[e] = bv;
        }
    }

    vfloat4 q = {r[0], r[1], r[2], r[3]};
    return q;
}

__global__ __launch_bounds__(256) void quant_af4_kernel(
    const float* __restrict__ x,
    const int* __restrict__ pctl_ptr,
    float* __restrict__ out,
    int n)
{
    const float percentile = (float)(*pctl_ptr);

    const int lane = threadIdx.x & 63;
    const int wpb  = blockDim.x >> 6;                       // waves per block
    const int wid  = blockIdx.x * wpb + (threadIdx.x >> 6); // global wave id
    const int nw   = gridDim.x * wpb;                       // total waves
    const int nseg = n >> 8;                                // 256 elems/segment

    int seg = wid;
    if (seg >= nseg) return;

    long long base = (long long)seg * 256 + lane * 4;
    vfloat4 v = *reinterpret_cast<const vfloat4*>(x + base);

    for (;;) {
        const int nextseg = seg + nw;
        const bool have_next = (nextseg < nseg);
        vfloat4 vn;
        if (have_next) {
            // prefetch next segment before touching v: load in flight
            // under the reduce+quantize of the current segment
            vn = *reinterpret_cast<const vfloat4*>(
                     x + (long long)nextseg * 256 + lane * 4);
        }

        const vfloat4 q = quantize_seg(v, percentile);
        __builtin_nontemporal_store(q, reinterpret_cast<vfloat4*>(out + base));

        if (!have_next) break;
        seg  = nextseg;
        base = (long long)seg * 256 + lane * 4;
        v    = vn;
    }
}

extern "C" void kernel_launch(void* const* d_in, const int* in_sizes, int n_in,
                              void* d_out, int out_size, void* d_ws, size_t ws_size,
                              hipStream_t stream) {
    const float* x    = (const float*)d_in[0];
    // d_in[1] = group_size (assumed 128, per setup_inputs; layout specialized)
    const int*   pctl = (const int*)d_in[2];
    float*       out  = (float*)d_out;

    const int n = out_size;              // 4096*4096
    const int threads = 256;
    // persistent: 2048 blocks = 8192 waves = 32 waves/CU (max occupancy);
    // each wave grid-strides over ~8 segments of 256 elements
    const int nseg = n >> 8;
    const int max_blocks = 2048;
    const int need_blocks = (nseg + (threads >> 6) - 1) / (threads >> 6);
    const int blocks = need_blocks < max_blocks ? need_blocks : max_blocks;

    quant_af4_kernel<<<blocks, threads, 0, stream>>>(x, pctl, out, n);
}

// Round 9
// 25.993 us; speedup vs baseline: 1.0488x; 1.0488x over previous
//
#include <hip/hip_runtime.h>

// AF4 group quantizer: 4096x4096 fp32, groups of 128 along columns.
// One wave = 256 contiguous elements = 2 groups; float4 per lane.
// Lanes 0..31 hold group A, lanes 32..63 group B.
// (Best measured structure: flat launch, 4 elems/lane — R7.)
//
// A/B this round: regular cached float4 stores instead of nontemporal
// (NT was introduced in R5 bundled with the V-scan and never isolated).
//
// Group min/max reduction: ds_swizzle xor16 (crosses the 16-lane boundary)
// + 4 DPP VALU steps (quad_perm xor1/xor2, row_half_mirror, row_mirror).
//
// Selection (fast path, smn<=0<=smx): magnitude-domain V-shape scan.
// d_k = fl(a - fl(sp*L_k)) is strictly V-shaped in fp32 (ladder gaps >=
// sp/12 >> ULP), so "take c_k when |d_k| < |d_{k-1}|" ends holding the
// argmin value with first-index tie behavior. Decisions bitwise-identical
// to the reference 16-candidate argmin (sign-split proof: for x>0 only the
// positive ladder or code 0 can win; dist to any negative code = |x|+|c|
// >= |x| = dist-to-0; ties keep the earlier index).

typedef float vfloat4 __attribute__((ext_vector_type(4)));

template <int CTRL>
__device__ __forceinline__ float dpp_mov_f32(float v) {
    return __int_as_float(__builtin_amdgcn_update_dpp(
        0, __float_as_int(v), CTRL, 0xF, 0xF, true));
}

__device__ __forceinline__ float swz_xor16_f32(float v) {
    return __int_as_float(__builtin_amdgcn_ds_swizzle(__float_as_int(v), 0x401F));
}

__global__ __launch_bounds__(256) void quant_af4_kernel(
    const float* __restrict__ x,
    const int* __restrict__ pctl_ptr,
    float* __restrict__ out,
    int n)
{
    const float LEV1 = (float)(1.0 / 12.0);
    const float LEV2 = (float)(1.0 / 6.0);
    const float LEV3 = (float)(1.0 / 4.0);
    const float LEV4 = (float)(1.0 / 3.0);
    const float LEV5 = (float)(1.0 / 2.0);
    const float LEV6 = (float)(2.0 / 3.0);
    const float LEV7 = 1.0f;

    const float percentile = (float)(*pctl_ptr);

    const int tid = blockIdx.x * blockDim.x + threadIdx.x;
    const long long base = (long long)tid * 4;
    if (base >= n) return;

    const vfloat4 v = *reinterpret_cast<const vfloat4*>(x + base);
    float vv[4] = {v.x, v.y, v.z, v.w};

    float mx = fmaxf(fmaxf(vv[0], vv[1]), fmaxf(vv[2], vv[3]));
    float mn = fminf(fminf(vv[0], vv[1]), fminf(vv[2], vv[3]));

    // 32-lane reduce-to-all: one DS round-trip + pure-VALU DPP chain
    mx = fmaxf(mx, swz_xor16_f32(mx));
    mn = fminf(mn, swz_xor16_f32(mn));
    mx = fmaxf(mx, dpp_mov_f32<0xB1>(mx));   // quad_perm xor1
    mn = fminf(mn, dpp_mov_f32<0xB1>(mn));
    mx = fmaxf(mx, dpp_mov_f32<0x4E>(mx));   // quad_perm xor2
    mn = fminf(mn, dpp_mov_f32<0x4E>(mn));
    mx = fmaxf(mx, dpp_mov_f32<0x141>(mx));  // row_half_mirror
    mn = fminf(mn, dpp_mov_f32<0x141>(mn));
    mx = fmaxf(mx, dpp_mov_f32<0x140>(mx));  // row_mirror
    mn = fminf(mn, dpp_mov_f32<0x140>(mn));

    const float smx  = mx * percentile;
    const float smn  = mn * percentile;
    const float nabs = -smn;  // exact sign flip

    float r[4];

    if (smn <= 0.0f && smx >= 0.0f) {
        #pragma unroll
        for (int e = 0; e < 4; ++e) {
            const float xv = vv[e];
            const float a  = fabsf(xv);
            const float sp = (xv > 0.0f) ? smx : nabs;
            float dprev = a;     // d_0 = a - sp*0
            float bv    = 0.0f;  // best code magnitude so far
            #pragma unroll
            for (int k = 1; k < 8; ++k) {
                const float L = (k == 1) ? LEV1 : (k == 2) ? LEV2 : (k == 3) ? LEV3
                              : (k == 4) ? LEV4 : (k == 5) ? LEV5 : (k == 6) ? LEV6
                              : LEV7;
                const float c = sp * L;          // == reference codebook value
                const float d = a - c;           // same fp32 diff as reference
                if (fabsf(d) < fabsf(dprev)) bv = c;  // V-shape: last win = argmin
                dprev = d;
            }
            const unsigned sb = __float_as_uint(xv) & 0x80000000u;
            r[e] = __uint_as_float(__float_as_uint(bv) | sb);
        }
    } else {
        // exact 16-candidate fallback (degenerate one-sided groups)
        float code[16];
        code[0]  = smn * 0.0f; code[1]  = smn * LEV1; code[2]  = smn * LEV2;
        code[3]  = smn * LEV3; code[4]  = smn * LEV4; code[5]  = smn * LEV5;
        code[6]  = smn * LEV6; code[7]  = smn * LEV7;
        code[8]  = smx * 0.0f; code[9]  = smx * LEV1; code[10] = smx * LEV2;
        code[11] = smx * LEV3; code[12] = smx * LEV4; code[13] = smx * LEV5;
        code[14] = smx * LEV6; code[15] = smx * LEV7;
        #pragma unroll
        for (int e = 0; e < 4; ++e) {
            const float xv = vv[e];
            float bd = fabsf(xv - code[0]);
            float bv = code[0];
            #pragma unroll
            for (int k = 1; k < 16; ++k) {
                const float d = fabsf(xv - code[k]);
                if (d < bd) { bd = d; bv = code[k]; }
            }
            r[e] = bv;
        }
    }

    vfloat4 q = {r[0], r[1], r[2], r[3]};
    *reinterpret_cast<vfloat4*>(out + base) = q;   // regular cached store (A/B vs NT)
}

extern "C" void kernel_launch(void* const* d_in, const int* in_sizes, int n_in,
                              void* d_out, int out_size, void* d_ws, size_t ws_size,
                              hipStream_t stream) {
    const float* x    = (const float*)d_in[0];
    // d_in[1] = group_size (assumed 128, per setup_inputs; layout specialized)
    const int*   pctl = (const int*)d_in[2];
    float*       out  = (float*)d_out;

    const int n = out_size;              // 4096*4096
    const int threads = 256;
    const int elems_per_block = threads * 4;
    const int blocks = (n + elems_per_block - 1) / elems_per_block;

    quant_af4_kernel<<<blocks, threads, 0, stream>>>(x, pctl, out, n);
}

// Round 10
// 25.385 us; speedup vs baseline: 1.0739x; 1.0240x over previous
//
#include <hip/hip_runtime.h>

// AF4 group quantizer: 4096x4096 fp32, groups of 128 along columns.
// One wave = 256 contiguous elements = 2 groups; float4 per lane.
// Lanes 0..31 hold group A, lanes 32..63 group B. NT stores (R9 A/B: NT
// beats cached by ~1 us). Flat launch, 4 elems/lane (best structure, R7).
//
// This round: packed dual-FP32. Element pairs processed as float2 ext-vectors
// so the scan's c=sp*L and d=a-c emit v_pk_mul_f32 / v_pk_add_f32 (2 elems
// per instruction). cmp/cndmask stay scalar (no packed cmp). Bitwise-identical
// numerics (pk halves are IEEE-identical to scalar ops, same order).
//
// Group min/max reduction: ds_swizzle xor16 (crosses the 16-lane boundary)
// + 4 DPP VALU steps (quad_perm xor1/xor2, row_half_mirror, row_mirror).
//
// Selection (fast path, smn<=0<=smx): magnitude-domain V-shape scan.
// d_k = fl(a - fl(sp*L_k)) is strictly V-shaped in fp32 (ladder gaps >=
// sp/12 >> ULP), so "take c_k when |d_k| < |d_{k-1}|" ends holding the
// argmin value with first-index tie behavior. Decisions bitwise-identical
// to the reference 16-candidate argmin (sign-split proof: for x>0 only the
// positive ladder or code 0 can win; dist to any negative code = |x|+|c|
// >= |x| = dist-to-0; ties keep the earlier index).

typedef float vfloat4 __attribute__((ext_vector_type(4)));
typedef float vfloat2 __attribute__((ext_vector_type(2)));

template <int CTRL>
__device__ __forceinline__ float dpp_mov_f32(float v) {
    return __int_as_float(__builtin_amdgcn_update_dpp(
        0, __float_as_int(v), CTRL, 0xF, 0xF, true));
}

__device__ __forceinline__ float swz_xor16_f32(float v) {
    return __int_as_float(__builtin_amdgcn_ds_swizzle(__float_as_int(v), 0x401F));
}

__global__ __launch_bounds__(256) void quant_af4_kernel(
    const float* __restrict__ x,
    const int* __restrict__ pctl_ptr,
    float* __restrict__ out,
    int n)
{
    const float LEV1 = (float)(1.0 / 12.0);
    const float LEV2 = (float)(1.0 / 6.0);
    const float LEV3 = (float)(1.0 / 4.0);
    const float LEV4 = (float)(1.0 / 3.0);
    const float LEV5 = (float)(1.0 / 2.0);
    const float LEV6 = (float)(2.0 / 3.0);
    const float LEV7 = 1.0f;

    const float percentile = (float)(*pctl_ptr);

    const int tid = blockIdx.x * blockDim.x + threadIdx.x;
    const long long base = (long long)tid * 4;
    if (base >= n) return;

    const vfloat4 v = *reinterpret_cast<const vfloat4*>(x + base);
    float vv[4] = {v.x, v.y, v.z, v.w};

    float mx = fmaxf(fmaxf(vv[0], vv[1]), fmaxf(vv[2], vv[3]));
    float mn = fminf(fminf(vv[0], vv[1]), fminf(vv[2], vv[3]));

    // 32-lane reduce-to-all: one DS round-trip + pure-VALU DPP chain
    mx = fmaxf(mx, swz_xor16_f32(mx));
    mn = fminf(mn, swz_xor16_f32(mn));
    mx = fmaxf(mx, dpp_mov_f32<0xB1>(mx));   // quad_perm xor1
    mn = fminf(mn, dpp_mov_f32<0xB1>(mn));
    mx = fmaxf(mx, dpp_mov_f32<0x4E>(mx));   // quad_perm xor2
    mn = fminf(mn, dpp_mov_f32<0x4E>(mn));
    mx = fmaxf(mx, dpp_mov_f32<0x141>(mx));  // row_half_mirror
    mn = fminf(mn, dpp_mov_f32<0x141>(mn));
    mx = fmaxf(mx, dpp_mov_f32<0x140>(mx));  // row_mirror
    mn = fminf(mn, dpp_mov_f32<0x140>(mn));

    const float smx  = mx * percentile;
    const float smn  = mn * percentile;
    const float nabs = -smn;  // exact sign flip

    float r[4];

    if (smn <= 0.0f && smx >= 0.0f) {
        #pragma unroll
        for (int p = 0; p < 2; ++p) {
            const float x0 = vv[2 * p + 0];
            const float x1 = vv[2 * p + 1];
            vfloat2 a2  = {fabsf(x0), fabsf(x1)};
            vfloat2 sp2 = {(x0 > 0.0f) ? smx : nabs,
                           (x1 > 0.0f) ? smx : nabs};
            vfloat2 dprev2 = a2;           // d_0 = a - sp*0
            vfloat2 bv2    = {0.0f, 0.0f}; // best code magnitudes so far
            #pragma unroll
            for (int k = 1; k < 8; ++k) {
                const float L = (k == 1) ? LEV1 : (k == 2) ? LEV2 : (k == 3) ? LEV3
                              : (k == 4) ? LEV4 : (k == 5) ? LEV5 : (k == 6) ? LEV6
                              : LEV7;
                const vfloat2 c2 = sp2 * L;   // v_pk_mul_f32: ref codebook values
                const vfloat2 d2 = a2 - c2;   // v_pk_add_f32(neg): ref fp32 diffs
                if (fabsf(d2.x) < fabsf(dprev2.x)) bv2.x = c2.x;  // V-shape argmin
                if (fabsf(d2.y) < fabsf(dprev2.y)) bv2.y = c2.y;
                dprev2 = d2;
            }
            const unsigned sb0 = __float_as_uint(x0) & 0x80000000u;
            const unsigned sb1 = __float_as_uint(x1) & 0x80000000u;
            r[2 * p + 0] = __uint_as_float(__float_as_uint(bv2.x) | sb0);
            r[2 * p + 1] = __uint_as_float(__float_as_uint(bv2.y) | sb1);
        }
    } else {
        // exact 16-candidate fallback (degenerate one-sided groups)
        float code[16];
        code[0]  = smn * 0.0f; code[1]  = smn * LEV1; code[2]  = smn * LEV2;
        code[3]  = smn * LEV3; code[4]  = smn * LEV4; code[5]  = smn * LEV5;
        code[6]  = smn * LEV6; code[7]  = smn * LEV7;
        code[8]  = smx * 0.0f; code[9]  = smx * LEV1; code[10] = smx * LEV2;
        code[11] = smx * LEV3; code[12] = smx * LEV4; code[13] = smx * LEV5;
        code[14] = smx * LEV6; code[15] = smx * LEV7;
        #pragma unroll
        for (int e = 0; e < 4; ++e) {
            const float xv = vv[e];
            float bd = fabsf(xv - code[0]);
            float bv = code[0];
            #pragma unroll
            for (int k = 1; k < 16; ++k) {
                const float d = fabsf(xv - code[k]);
                if (d < bd) { bd = d; bv = code[k]; }
            }
            r[e] = bv;
        }
    }

    vfloat4 q = {r[0], r[1], r[2], r[3]};
    __builtin_nontemporal_store(q, reinterpret_cast<vfloat4*>(out + base));
}

extern "C" void kernel_launch(void* const* d_in, const int* in_sizes, int n_in,
                              void* d_out, int out_size, void* d_ws, size_t ws_size,
                              hipStream_t stream) {
    const float* x    = (const float*)d_in[0];
    // d_in[1] = group_size (assumed 128, per setup_inputs; layout specialized)
    const int*   pctl = (const int*)d_in[2];
    float*       out  = (float*)d_out;

    const int n = out_size;              // 4096*4096
    const int threads = 256;
    const int elems_per_block = threads * 4;
    const int blocks = (n + elems_per_block - 1) / elems_per_block;

    quant_af4_kernel<<<blocks, threads, 0, stream>>>(x, pctl, out, n);
}